// Round 14
// baseline (480.360 us; speedup 1.0000x reference)
//
#include <hip/hip_runtime.h>
#include <math.h>

typedef unsigned int u32;
typedef unsigned short u16;
typedef __attribute__((ext_vector_type(8))) short short8;
typedef __attribute__((ext_vector_type(4))) float f32x4;

__device__ __forceinline__ u16 f2bf(float f) {
  u32 u = __builtin_bit_cast(u32, f);
  u += 0x7FFFu + ((u >> 16) & 1u);
  return (u16)(u >> 16);
}
__device__ __forceinline__ float bf2f(u16 h) {
  u32 u = ((u32)h) << 16;
  return __builtin_bit_cast(float, u);
}
__device__ __forceinline__ void gload_lds16(const void* g, void* l) {
  __builtin_amdgcn_global_load_lds((const __attribute__((address_space(1))) u32*)g,
                                   (__attribute__((address_space(3))) u32*)l, 16, 0, 0);
}
__device__ __forceinline__ f32x4 mfma16(short8 a, short8 b, f32x4 c) {
  return __builtin_amdgcn_mfma_f32_16x16x32_bf16(a, b, c, 0, 0, 0);
}

// ------- transpose+cast (4 square weights, z-indexed): fp32 [K][N] -> bf16 [N][K] -------
__global__ __launch_bounds__(256) void transpose_cast4(const float* __restrict__ Wq,
                                                       const float* __restrict__ Wk,
                                                       const float* __restrict__ Wv,
                                                       const float* __restrict__ Wp,
                                                       u16* __restrict__ wqkvT,
                                                       u16* __restrict__ wpT) {
  __shared__ __attribute__((aligned(16))) u16 tile[64][72];
  const int z = blockIdx.z;
  const float* src = (z == 0) ? Wq : (z == 1) ? Wk : (z == 2) ? Wv : Wp;
  u16* dst = (z < 3) ? (wqkvT + (size_t)z * 2048 * 2048) : wpT;
  const int n0 = blockIdx.x * 64, k0 = blockIdx.y * 64;
  const int t = threadIdx.x;
  const int tr = t >> 4;
  const int tc4 = (t & 15) * 4;
#pragma unroll
  for (int p = 0; p < 4; ++p) {
    int row = p * 16 + tr;
    const float4 v = *(const float4*)(src + (size_t)(k0 + row) * 2048 + n0 + tc4);
    tile[tc4 + 0][row] = f2bf(v.x);
    tile[tc4 + 1][row] = f2bf(v.y);
    tile[tc4 + 2][row] = f2bf(v.z);
    tile[tc4 + 3][row] = f2bf(v.w);
  }
  __syncthreads();
  const int nr = t >> 2;
  const int kc = (t & 3) * 16;
  u16* d = dst + (size_t)(n0 + nr) * 2048 + k0 + kc;
  *(short8*)(d) = *(const short8*)&tile[nr][kc];
  *(short8*)(d + 8) = *(const short8*)&tile[nr][kc + 8];
}

// ------- transpose+cast W1 & W2 (z-indexed): fp32 [K][N] -> bf16 [N][K] ----------------
__global__ __launch_bounds__(256) void transpose_w12(const float* __restrict__ W1,
                                                     const float* __restrict__ W2,
                                                     u16* __restrict__ w1T,
                                                     u16* __restrict__ w2T) {
  __shared__ __attribute__((aligned(16))) u16 tile[64][72];
  const int z = blockIdx.z;
  const float* src = z ? W2 : W1;
  u16* dst = z ? w2T : w1T;
  const int K = z ? 8192 : 2048;
  const int N = z ? 2048 : 8192;
  const int n0 = (z ? blockIdx.y : blockIdx.x) * 64;
  const int k0 = (z ? blockIdx.x : blockIdx.y) * 64;
  const int t = threadIdx.x;
  const int tr = t >> 4;
  const int tc4 = (t & 15) * 4;
#pragma unroll
  for (int p = 0; p < 4; ++p) {
    int row = p * 16 + tr;
    const float4 v = *(const float4*)(src + (size_t)(k0 + row) * N + n0 + tc4);
    tile[tc4 + 0][row] = f2bf(v.x);
    tile[tc4 + 1][row] = f2bf(v.y);
    tile[tc4 + 2][row] = f2bf(v.z);
    tile[tc4 + 3][row] = f2bf(v.w);
  }
  __syncthreads();
  const int nr = t >> 2;
  const int kc = (t & 3) * 16;
  u16* d = dst + (size_t)(n0 + nr) * K + k0 + kc;
  *(short8*)(d) = *(const short8*)&tile[nr][kc];
  *(short8*)(d + 8) = *(const short8*)&tile[nr][kc + 8];
}

// ---------------- transpose V out of qkv: -> vT[h][d][kv] ----------------
__global__ __launch_bounds__(256) void transpose_v(const u16* __restrict__ qkv,
                                                   u16* __restrict__ vT) {
  __shared__ __attribute__((aligned(16))) u16 tile[64][72];
  const int kv0 = blockIdx.x * 64, d0 = blockIdx.y * 64, h = blockIdx.z;
  const int t = threadIdx.x;
  const int tr = t >> 3;
  const int tc8 = (t & 7) * 8;
#pragma unroll
  for (int p = 0; p < 2; ++p) {
    int row = p * 32 + tr;
    short8 v = *(const short8*)(qkv + (size_t)(kv0 + row) * 6144 + 4096 + h * 128 + d0 + tc8);
#pragma unroll
    for (int j = 0; j < 8; ++j) tile[tc8 + j][row] = (u16)v[j];
  }
  __syncthreads();
  const int dr = t >> 2;
  const int kc = (t & 3) * 16;
  u16* dst = vT + ((size_t)h * 128 + d0 + dr) * 2048 + kv0 + kc;
  *(short8*)dst = *(const short8*)&tile[dr][kc];
  *(short8*)(dst + 8) = *(const short8*)&tile[dr][kc + 8];
}

// ---------------- LayerNorm: fp32 [2048 rows][2048] -> bf16 ----------------
__global__ __launch_bounds__(256) void ln_kernel(const float* __restrict__ x,
                                                 const float* __restrict__ gw,
                                                 const float* __restrict__ bw,
                                                 u16* __restrict__ out) {
  const int row = blockIdx.x, t = threadIdx.x;
  const float* xr = x + (size_t)row * 2048;
  const float4 v0 = *(const float4*)(xr + t * 8);
  const float4 v1 = *(const float4*)(xr + t * 8 + 4);
  float s = v0.x + v0.y + v0.z + v0.w + v1.x + v1.y + v1.z + v1.w;
  float q = v0.x * v0.x + v0.y * v0.y + v0.z * v0.z + v0.w * v0.w +
            v1.x * v1.x + v1.y * v1.y + v1.z * v1.z + v1.w * v1.w;
#pragma unroll
  for (int w = 32; w; w >>= 1) { s += __shfl_xor(s, w); q += __shfl_xor(q, w); }
  __shared__ float rs[4], rq[4];
  const int wid = t >> 6, lane = t & 63;
  if (!lane) { rs[wid] = s; rq[wid] = q; }
  __syncthreads();
  s = rs[0] + rs[1] + rs[2] + rs[3];
  q = rq[0] + rq[1] + rq[2] + rq[3];
  const float mu = s * (1.f / 2048.f);
  const float var = q * (1.f / 2048.f) - mu * mu;
  const float rstd = rsqrtf(var + 1e-5f);
  const float4 g0 = *(const float4*)(gw + t * 8);
  const float4 g1 = *(const float4*)(gw + t * 8 + 4);
  const float4 b0 = *(const float4*)(bw + t * 8);
  const float4 b1 = *(const float4*)(bw + t * 8 + 4);
  short8 o;
  o[0] = (short)f2bf((v0.x - mu) * rstd * g0.x + b0.x);
  o[1] = (short)f2bf((v0.y - mu) * rstd * g0.y + b0.y);
  o[2] = (short)f2bf((v0.z - mu) * rstd * g0.z + b0.z);
  o[3] = (short)f2bf((v0.w - mu) * rstd * g0.w + b0.w);
  o[4] = (short)f2bf((v1.x - mu) * rstd * g1.x + b1.x);
  o[5] = (short)f2bf((v1.y - mu) * rstd * g1.y + b1.y);
  o[6] = (short)f2bf((v1.z - mu) * rstd * g1.z + b1.z);
  o[7] = (short)f2bf((v1.w - mu) * rstd * g1.w + b1.w);
  *(short8*)(out + (size_t)row * 2048 + t * 8) = o;
}

// ------- fused split-K reduce + LayerNorm: x1 = sum(partials)+bias+x; g = LN(x1) -------
__global__ __launch_bounds__(256) void reduce_ln(const float* __restrict__ pA,
                                                 const float* __restrict__ pB,
                                                 const float* __restrict__ bias,
                                                 const float* __restrict__ res1,
                                                 const float* __restrict__ gw,
                                                 const float* __restrict__ bw,
                                                 float* __restrict__ x1,
                                                 u16* __restrict__ g) {
  const int row = blockIdx.x, t = threadIdx.x;
  const size_t MN = 4194304;
  const size_t base = (size_t)row * 2048 + t * 8;
  float v[8];
#pragma unroll
  for (int half = 0; half < 2; ++half) {
    float4 a0 = *(const float4*)(pA + base + half * 4);
    float4 a1 = *(const float4*)(pA + MN + base + half * 4);
    float4 b0 = *(const float4*)(pB + base + half * 4);
    float4 b1 = *(const float4*)(pB + MN + base + half * 4);
    float4 bi = *(const float4*)(bias + t * 8 + half * 4);
    float4 r1 = *(const float4*)(res1 + base + half * 4);
    v[half * 4 + 0] = a0.x + a1.x + b0.x + b1.x + bi.x + r1.x;
    v[half * 4 + 1] = a0.y + a1.y + b0.y + b1.y + bi.y + r1.y;
    v[half * 4 + 2] = a0.z + a1.z + b0.z + b1.z + bi.z + r1.z;
    v[half * 4 + 3] = a0.w + a1.w + b0.w + b1.w + bi.w + r1.w;
  }
  float4 o0 = {v[0], v[1], v[2], v[3]}, o1 = {v[4], v[5], v[6], v[7]};
  *(float4*)(x1 + base) = o0;
  *(float4*)(x1 + base + 4) = o1;
  float s = 0.f, q = 0.f;
#pragma unroll
  for (int j = 0; j < 8; ++j) { s += v[j]; q += v[j] * v[j]; }
#pragma unroll
  for (int w = 32; w; w >>= 1) { s += __shfl_xor(s, w); q += __shfl_xor(q, w); }
  __shared__ float rs[4], rq[4];
  const int wid = t >> 6, lane = t & 63;
  if (!lane) { rs[wid] = s; rq[wid] = q; }
  __syncthreads();
  s = rs[0] + rs[1] + rs[2] + rs[3];
  q = rq[0] + rq[1] + rq[2] + rq[3];
  const float mu = s * (1.f / 2048.f);
  const float var = q * (1.f / 2048.f) - mu * mu;
  const float rstd = rsqrtf(var + 1e-5f);
  short8 o;
#pragma unroll
  for (int j = 0; j < 8; ++j) {
    float gj = *(gw + t * 8 + j);
    float bj = *(bw + t * 8 + j);
    o[j] = (short)f2bf((v[j] - mu) * rstd * gj + bj);
  }
  *(short8*)(g + base) = o;
}

// ---------------- GEMM v3 (best): 256x256, BK=32, 8 waves (2Mx4N), triple-buffer -------
// EPI 2 epilogue now uses tanh-GELU (x * sigmoid(2u)) via __expf instead of erff.
template <int EPI>
__global__ __launch_bounds__(512, 2) void gemm3(const u16* __restrict__ A,
                                                const u16* __restrict__ Bt,
                                                int M, int N, int K, int Kc,
                                                u16* __restrict__ outB,
                                                const float* __restrict__ bias,
                                                float* __restrict__ pA,
                                                float* __restrict__ pB) {
  __shared__ __attribute__((aligned(16))) u16 lds[3 * 16384];
  const int m0 = blockIdx.y * 256, n0 = blockIdx.x * 256;
  const int tid = threadIdx.x, wid = tid >> 6, lane = tid & 63;
  const int wr = wid >> 2, wc = wid & 3;
  const int lq = lane & 15, lk = lane >> 4;
  const int kStart = blockIdx.z * Kc;
  const int NT = Kc / 32;

  size_t aoff[2], boff[2];
#pragma unroll
  for (int s = 0; s < 2; ++s) {
    int c = s * 512 + tid;
    int row = c >> 2;
    int col = ((c & 3) ^ ((row >> 1) & 3)) * 8;
    aoff[s] = (size_t)(m0 + row) * K + kStart + col;
    boff[s] = (size_t)(n0 + row) * K + kStart + col;
  }
  u16* ldst = lds + tid * 8;

#define STA(s, buf, t2) gload_lds16(A + aoff[s] + (size_t)((t2) * 32), \
                                    ldst + (buf) * 16384 + (s) * 4096)
#define STB(s, buf, t2) gload_lds16(Bt + boff[s] + (size_t)((t2) * 32), \
                                    ldst + (buf) * 16384 + 8192 + (s) * 4096)

  STA(0, 0, 0); STA(1, 0, 0); STB(0, 0, 0); STB(1, 0, 0);
  STA(0, 1, 1); STA(1, 1, 1); STB(0, 1, 1); STB(1, 1, 1);
  asm volatile("s_waitcnt vmcnt(4)" ::: "memory");
  __builtin_amdgcn_s_barrier();
  __builtin_amdgcn_sched_barrier(0);

  f32x4 acc[8][4] = {};
  int cur = 0, nxt2 = 2;
  for (int t = 0; t < NT; ++t) {
    const char* bufc = (const char*)lds + cur * 32768;
    const bool st = (t + 2) < NT;
    short8 bf[4], af[4];
#pragma unroll
    for (int ni = 0; ni < 4; ++ni) {
      int br = wc * 64 + ni * 16 + lq;
      bf[ni] = *(const short8*)(bufc + 16384 + br * 64 + ((lk ^ ((br >> 1) & 3)) << 4));
    }
#pragma unroll
    for (int mi = 0; mi < 4; ++mi) {
      int ar = wr * 128 + mi * 16 + lq;
      af[mi] = *(const short8*)(bufc + ar * 64 + ((lk ^ ((ar >> 1) & 3)) << 4));
    }
    if (st) { STA(0, nxt2, t + 2); STA(1, nxt2, t + 2); }
    __builtin_amdgcn_s_setprio(1);
#pragma unroll
    for (int mi = 0; mi < 4; ++mi)
#pragma unroll
      for (int ni = 0; ni < 4; ++ni)
        acc[mi][ni] = mfma16(af[mi], bf[ni], acc[mi][ni]);
    __builtin_amdgcn_s_setprio(0);
#pragma unroll
    for (int mi = 0; mi < 4; ++mi) {
      int ar = wr * 128 + (mi + 4) * 16 + lq;
      af[mi] = *(const short8*)(bufc + ar * 64 + ((lk ^ ((ar >> 1) & 3)) << 4));
    }
    if (st) { STB(0, nxt2, t + 2); STB(1, nxt2, t + 2); }
    __builtin_amdgcn_s_setprio(1);
#pragma unroll
    for (int mi = 0; mi < 4; ++mi)
#pragma unroll
      for (int ni = 0; ni < 4; ++ni)
        acc[mi + 4][ni] = mfma16(af[mi], bf[ni], acc[mi + 4][ni]);
    __builtin_amdgcn_s_setprio(0);
    if (st) asm volatile("s_waitcnt vmcnt(4)" ::: "memory");
    else    asm volatile("s_waitcnt vmcnt(0)" ::: "memory");
    __builtin_amdgcn_s_barrier();
    __builtin_amdgcn_sched_barrier(0);
    cur = (cur == 2) ? 0 : cur + 1;
    nxt2 = (nxt2 == 2) ? 0 : nxt2 + 1;
  }
#undef STA
#undef STB

  float* pp = nullptr;
  if (EPI == 4) {
    pp = (blockIdx.z < 2 ? pA : pB) + (size_t)(blockIdx.z & 1) * ((size_t)M * N);
  }
#pragma unroll
  for (int mi = 0; mi < 8; ++mi) {
#pragma unroll
    for (int ni = 0; ni < 4; ++ni) {
      const int col = n0 + wc * 64 + ni * 16 + lq;
#pragma unroll
      for (int r = 0; r < 4; ++r) {
        const int row = m0 + wr * 128 + mi * 16 + lk * 4 + r;
        const size_t idx = (size_t)row * N + col;
        float v = acc[mi][ni][r];
        if (EPI == 0) {
          outB[idx] = f2bf(v);
        } else if (EPI == 2) {
          float xg = v + bias[col];
          float u = 0.7978845608f * (xg + 0.044715f * xg * xg * xg);
          outB[idx] = f2bf(xg / (1.f + __expf(-2.f * u)));
        } else {
          pp[idx] = v;
        }
      }
    }
  }
}

// ---------------- GEMM v5 (QKV): 256x128 tile, BK=32, 8 waves (4Mx2N), 72KB ------------
template <int EPI>
__global__ __launch_bounds__(512, 4) void gemm5(const u16* __restrict__ A,
                                                const u16* __restrict__ Bt,
                                                int M, int N, int K, int Kc,
                                                u16* __restrict__ outB,
                                                const float* __restrict__ bias,
                                                float* __restrict__ pA,
                                                float* __restrict__ pB) {
  __shared__ __attribute__((aligned(16))) u16 lds[3 * 12288];
  const int m0 = blockIdx.y * 256, n0 = blockIdx.x * 128;
  const int tid = threadIdx.x, wid = tid >> 6, lane = tid & 63;
  const int wr = wid >> 1, wc = wid & 1;
  const int lq = lane & 15, lk = lane >> 4;
  const int kStart = blockIdx.z * Kc;
  const int NT = Kc / 32;

  size_t aoff[2], boff;
#pragma unroll
  for (int s = 0; s < 2; ++s) {
    int c = s * 512 + tid;
    int row = c >> 2;
    int col = ((c & 3) ^ ((row >> 1) & 3)) * 8;
    aoff[s] = (size_t)(m0 + row) * K + kStart + col;
  }
  {
    int row = tid >> 2;
    int col = ((tid & 3) ^ ((row >> 1) & 3)) * 8;
    boff = (size_t)(n0 + row) * K + kStart + col;
  }
  u16* ldst = lds + tid * 8;

#define STA(s, buf, t2) gload_lds16(A + aoff[s] + (size_t)((t2) * 32), \
                                    ldst + (buf) * 12288 + (s) * 4096)
#define STB(buf, t2) gload_lds16(Bt + boff + (size_t)((t2) * 32), \
                                 ldst + (buf) * 12288 + 8192)

  STA(0, 0, 0); STA(1, 0, 0); STB(0, 0);
  STA(0, 1, 1); STA(1, 1, 1); STB(1, 1);
  asm volatile("s_waitcnt vmcnt(3)" ::: "memory");
  __builtin_amdgcn_s_barrier();
  __builtin_amdgcn_sched_barrier(0);

  f32x4 acc[4][4] = {};
  int cur = 0, nxt2 = 2;
  for (int t = 0; t < NT; ++t) {
    const char* bufc = (const char*)lds + cur * 24576;
    const bool st = (t + 2) < NT;
    short8 bf[4], af[4];
#pragma unroll
    for (int ni = 0; ni < 4; ++ni) {
      int br = wc * 64 + ni * 16 + lq;
      bf[ni] = *(const short8*)(bufc + 16384 + br * 64 + ((lk ^ ((br >> 1) & 3)) << 4));
    }
#pragma unroll
    for (int mi = 0; mi < 4; ++mi) {
      int ar = wr * 64 + mi * 16 + lq;
      af[mi] = *(const short8*)(bufc + ar * 64 + ((lk ^ ((ar >> 1) & 3)) << 4));
    }
    if (st) { STA(0, nxt2, t + 2); STA(1, nxt2, t + 2); STB(nxt2, t + 2); }
    __builtin_amdgcn_s_setprio(1);
#pragma unroll
    for (int mi = 0; mi < 4; ++mi)
#pragma unroll
      for (int ni = 0; ni < 4; ++ni)
        acc[mi][ni] = mfma16(af[mi], bf[ni], acc[mi][ni]);
    __builtin_amdgcn_s_setprio(0);
    if (st) asm volatile("s_waitcnt vmcnt(3)" ::: "memory");
    else    asm volatile("s_waitcnt vmcnt(0)" ::: "memory");
    __builtin_amdgcn_s_barrier();
    __builtin_amdgcn_sched_barrier(0);
    cur = (cur == 2) ? 0 : cur + 1;
    nxt2 = (nxt2 == 2) ? 0 : nxt2 + 1;
  }
#undef STA
#undef STB

  float* pp = nullptr;
  if (EPI == 4) {
    pp = (blockIdx.z < 2 ? pA : pB) + (size_t)(blockIdx.z & 1) * ((size_t)M * N);
  }
#pragma unroll
  for (int mi = 0; mi < 4; ++mi) {
#pragma unroll
    for (int ni = 0; ni < 4; ++ni) {
      const int col = n0 + wc * 64 + ni * 16 + lq;
#pragma unroll
      for (int r = 0; r < 4; ++r) {
        const int row = m0 + wr * 64 + mi * 16 + lk * 4 + r;
        const size_t idx = (size_t)row * N + col;
        float v = acc[mi][ni][r];
        if (EPI == 0) {
          outB[idx] = f2bf(v);
        } else if (EPI == 2) {
          float xg = v + bias[col];
          float u = 0.7978845608f * (xg + 0.044715f * xg * xg * xg);
          outB[idx] = f2bf(xg / (1.f + __expf(-2.f * u)));
        } else {
          pp[idx] = v;
        }
      }
    }
  }
}

// ---------------- split-K reduce: out = sum partials + bias + res1 (+ bf(res2)) --------
template <int NS, int RES2>
__global__ __launch_bounds__(256) void reduce_kernel(const float* __restrict__ pA,
                                                     const float* __restrict__ pB,
                                                     const float* __restrict__ bias,
                                                     const float* __restrict__ res1,
                                                     const u16* __restrict__ res2,
                                                     float* __restrict__ out,
                                                     int MN, int N) {
  const int i = (blockIdx.x * 256 + threadIdx.x) * 4;
  if (i >= MN) return;
  float4 s = *(const float4*)(pA + i);
  {
    const float4 t = *(const float4*)(pA + MN + i);
    s.x += t.x; s.y += t.y; s.z += t.z; s.w += t.w;
  }
  if (NS == 4) {
    const float4 t0 = *(const float4*)(pB + i);
    const float4 t1 = *(const float4*)(pB + MN + i);
    s.x += t0.x + t1.x; s.y += t0.y + t1.y; s.z += t0.z + t1.z; s.w += t0.w + t1.w;
  }
  const int col = i & (N - 1);
  const float4 bv = *(const float4*)(bias + col);
  const float4 r1 = *(const float4*)(res1 + i);
  float4 o;
  o.x = s.x + bv.x + r1.x;
  o.y = s.y + bv.y + r1.y;
  o.z = s.z + bv.z + r1.z;
  o.w = s.w + bv.w + r1.w;
  if (RES2) {
    const u16* r2 = res2 + i;
    o.x += bf2f(r2[0]); o.y += bf2f(r2[1]); o.z += bf2f(r2[2]); o.w += bf2f(r2[3]);
  }
  *(float4*)(out + i) = o;
}

// ------- flash attention (causal), split-KV x2, 4 waves x 16 q-rows, KVBLK=64 ----------
// NO K/V LDS staging: fragments read directly from global (L2-resident; KV/head = 1MB).
// No barriers at all — waves fully independent. lsP stays (per-wave P round-trip).
__global__ __launch_bounds__(256) void attn_kernel(const u16* __restrict__ qkv,
                                                   const u16* __restrict__ vT,
                                                   float* __restrict__ po,
                                                   float* __restrict__ pm,
                                                   float* __restrict__ pl) {
  __shared__ __attribute__((aligned(16))) u16 lsP[4][16 * 64];
  const int h = blockIdx.x;
  const int c = blockIdx.y;
  const int qi = 31 - blockIdx.z;
  const int qb = qi * 64;
  const int tid = threadIdx.x, wid = tid >> 6, lane = tid & 63;
  const int lq = lane & 15, lk = lane >> 4;
  const int qw = qb + wid * 16;

  const int nkt = qi + 1;
  const int ch0 = (nkt + 1) >> 1;
  const int base = c ? ch0 : 0;
  const int cnt = c ? (nkt - ch0) : ch0;

  short8 qf[4];
  {
    const u16* qp = qkv + (size_t)(qw + lq) * 6144 + h * 128;
#pragma unroll
    for (int ks = 0; ks < 4; ++ks) qf[ks] = *(const short8*)(qp + ks * 32 + lk * 8);
  }
  float mreg[4], lreg[4];
  f32x4 o[8];
#pragma unroll
  for (int r = 0; r < 4; ++r) { mreg[r] = -INFINITY; lreg[r] = 0.f; }
#pragma unroll
  for (int dt = 0; dt < 8; ++dt) o[dt] = (f32x4){0.f, 0.f, 0.f, 0.f};

  // direct-read base pointers for this lane
  const u16* kbase = qkv + 2048 + h * 128 + (size_t)lq * 6144 + lk * 8;   // + kv*6144 + ks*32
  const u16* vbase = vT + ((size_t)h * 128 + lq) * 2048 + lk * 8;         // + dt*16*2048 + kv0 + kk*32

  for (int it = 0; it < cnt; ++it) {
    const int kt = base + it;
    const int kv0 = kt * 64;

    // QK^T (S tile 16x64) — K fragments direct from global (L2)
    f32x4 sc[4];
#pragma unroll
    for (int nt = 0; nt < 4; ++nt) sc[nt] = (f32x4){0.f, 0.f, 0.f, 0.f};
#pragma unroll
    for (int ks = 0; ks < 4; ++ks) {
#pragma unroll
      for (int nt = 0; nt < 4; ++nt) {
        short8 kf = *(const short8*)(kbase + (size_t)(kv0 + nt * 16) * 6144 + ks * 32);
        sc[nt] = mfma16(qf[ks], kf, sc[nt]);
      }
    }
    // scale + causal mask + row max
    float rmax[4] = {-INFINITY, -INFINITY, -INFINITY, -INFINITY};
#pragma unroll
    for (int nt = 0; nt < 4; ++nt) {
      int kv = kv0 + nt * 16 + lq;
#pragma unroll
      for (int r = 0; r < 4; ++r) {
        int qrow = qw + lk * 4 + r;
        float s = (kv <= qrow) ? sc[nt][r] * 0.08838834764831845f : -INFINITY;
        sc[nt][r] = s;
        rmax[r] = fmaxf(rmax[r], s);
      }
    }
#pragma unroll
    for (int r = 0; r < 4; ++r)
#pragma unroll
      for (int w = 1; w < 16; w <<= 1) rmax[r] = fmaxf(rmax[r], __shfl_xor(rmax[r], w));
    // T13 defer-max
    bool grow = false;
#pragma unroll
    for (int r = 0; r < 4; ++r) grow |= (rmax[r] > mreg[r] + 8.f);
    if (__any(grow)) {
#pragma unroll
      for (int r = 0; r < 4; ++r) {
        float mn = fmaxf(mreg[r], rmax[r]);
        float alpha = __expf(mreg[r] - mn);
        mreg[r] = mn;
        lreg[r] *= alpha;
#pragma unroll
        for (int dt = 0; dt < 8; ++dt) o[dt][r] *= alpha;
      }
    }
    float rsum[4] = {0.f, 0.f, 0.f, 0.f};
    u16* P = &lsP[wid][0];
#pragma unroll
    for (int nt = 0; nt < 4; ++nt) {
#pragma unroll
      for (int r = 0; r < 4; ++r) {
        float p = __expf(sc[nt][r] - mreg[r]);
        rsum[r] += p;
        int prow = lk * 4 + r, pcol = nt * 16 + lq;
        *(u16*)((char*)P + prow * 128 + ((pcol * 2) ^ ((prow & 7) << 4))) = f2bf(p);
      }
    }
#pragma unroll
    for (int r = 0; r < 4; ++r) {
#pragma unroll
      for (int w = 1; w < 16; w <<= 1) rsum[r] += __shfl_xor(rsum[r], w);
      lreg[r] += rsum[r];
    }
    // PV — V fragments direct from global (L2)
#pragma unroll
    for (int kk = 0; kk < 2; ++kk) {
      short8 pa = *(const short8*)((const char*)P + lq * 128 +
                                   ((kk * 64 + lk * 16) ^ ((lq & 7) << 4)));
#pragma unroll
      for (int dt = 0; dt < 8; ++dt) {
        short8 vf = *(const short8*)(vbase + (size_t)(dt * 16) * 2048 + kv0 + kk * 32);
        o[dt] = mfma16(pa, vf, o[dt]);
      }
    }
  }
#pragma unroll
  for (int r = 0; r < 4; ++r) {
    int row = qw + lk * 4 + r;
    float* op = po + (size_t)c * 4194304 + ((size_t)h * 2048 + row) * 128 + lq;
#pragma unroll
    for (int dt = 0; dt < 8; ++dt) op[dt * 16] = o[dt][r];
    if (lq == 0) {
      pm[c * 32768 + h * 2048 + row] = mreg[r];
      pl[c * 32768 + h * 2048 + row] = lreg[r];
    }
  }
}

// ---------------- merge split-KV partials -> attn bf16 [row][h*128+d] ----------------
__global__ __launch_bounds__(256) void attn_merge(const float* __restrict__ po,
                                                  const float* __restrict__ pm,
                                                  const float* __restrict__ pl,
                                                  u16* __restrict__ attn) {
  const int e = (blockIdx.x * 256 + threadIdx.x) * 4;
  const int hrow = e >> 7;
  const int d = e & 127;
  const int h = hrow >> 11, row = hrow & 2047;
  float m0 = pm[hrow], m1 = pm[32768 + hrow];
  float l0 = pl[hrow], l1 = pl[32768 + hrow];
  float m = fmaxf(m0, m1);
  float w0 = __expf(m0 - m), w1 = __expf(m1 - m);
  float inv = 1.f / (l0 * w0 + l1 * w1);
  float4 o0 = *(const float4*)(po + e);
  float4 o1 = *(const float4*)(po + 4194304 + e);
  u16* op = attn + (size_t)row * 2048 + h * 128 + d;
  op[0] = f2bf((o0.x * w0 + o1.x * w1) * inv);
  op[1] = f2bf((o0.y * w0 + o1.y * w1) * inv);
  op[2] = f2bf((o0.z * w0 + o1.z * w1) * inv);
  op[3] = f2bf((o0.w * w0 + o1.w * w1) * inv);
}

extern "C" void kernel_launch(void* const* d_in, const int* in_sizes, int n_in,
                              void* d_out, int out_size, void* d_ws, size_t ws_size,
                              hipStream_t stream) {
  (void)in_sizes; (void)n_in; (void)out_size; (void)ws_size;
  const float* x    = (const float*)d_in[0];
  const float* ln1g = (const float*)d_in[1];
  const float* ln1b = (const float*)d_in[2];
  const float* Wq   = (const float*)d_in[3];
  const float* Wk   = (const float*)d_in[4];
  const float* Wv   = (const float*)d_in[5];
  const float* Wp   = (const float*)d_in[6];
  const float* bp   = (const float*)d_in[7];
  const float* ln2g = (const float*)d_in[8];
  const float* ln2b = (const float*)d_in[9];
  const float* W1   = (const float*)d_in[10];
  const float* b1   = (const float*)d_in[11];
  const float* W2   = (const float*)d_in[12];
  const float* b2   = (const float*)d_in[13];
  float* out = (float*)d_out;
  char* ws = (char*)d_ws;

  u16* wqkvT = (u16*)(ws + 0);
  u16* hbuf  = (u16*)(ws + 25165824);
  u16* wpT   = (u16*)(ws + 33554432);
  u16* w1T   = (u16*)(ws + 41943040);
  u16* w2T   = (u16*)(ws + 75497472);
  u16* qkv   = (u16*)(ws + 109051904);
  u16* vT    = (u16*)(ws + 134217728);
  u16* attn  = (u16*)(ws + 142606336);
  float* x1  = (float*)(ws + 150994944);
  u16* g     = (u16*)(ws + 167772160);
  u16* ff1   = (u16*)(ws + 0);
  float* po = (float*)(ws + 0);
  float* pm = (float*)(ws + 167772160);
  float* pl = (float*)(ws + 167772160 + 262144);
  float* projPA = (float*)(ws + 0);
  float* projPB = (float*)(ws + 109051904);
  float* ffPA = (float*)(ws + 33554432);
  float* ffPB = (float*)(ws + 109051904);

  dim3 b256(256), b512(512);
  transpose_cast4<<<dim3(32, 32, 4), b256, 0, stream>>>(Wq, Wk, Wv, Wp, wqkvT, wpT);
  transpose_w12<<<dim3(128, 32, 2), b256, 0, stream>>>(W1, W2, w1T, w2T);
  ln_kernel<<<2048, b256, 0, stream>>>(x, ln1g, ln1b, hbuf);
  gemm5<0><<<dim3(48, 8, 1), b512, 0, stream>>>(hbuf, wqkvT, 2048, 6144, 2048, 2048,
                                                qkv, nullptr, nullptr, nullptr);
  transpose_v<<<dim3(32, 2, 16), b256, 0, stream>>>(qkv, vT);
  attn_kernel<<<dim3(16, 2, 32), b256, 0, stream>>>(qkv, vT, po, pm, pl);
  attn_merge<<<4096, b256, 0, stream>>>(po, pm, pl, attn);
  gemm3<4><<<dim3(8, 8, 4), b512, 0, stream>>>(attn, wpT, 2048, 2048, 2048, 512,
                                               nullptr, nullptr, projPA, projPB);
  reduce_ln<<<2048, b256, 0, stream>>>(projPA, projPB, bp, x, ln2g, ln2b, x1, g);
  gemm3<2><<<dim3(32, 8, 1), b512, 0, stream>>>(g, w1T, 2048, 8192, 2048, 2048,
                                                ff1, b1, nullptr, nullptr);
  gemm3<4><<<dim3(8, 8, 4), b512, 0, stream>>>(ff1, w2T, 2048, 2048, 8192, 2048,
                                               nullptr, nullptr, ffPA, ffPB);
  reduce_kernel<4, 1><<<4096, b256, 0, stream>>>(ffPA, ffPB, b2, x1, g, out,
                                                 4194304, 2048);
}

// Round 15
// 390.412 us; speedup vs baseline: 1.2304x; 1.2304x over previous
//
#include <hip/hip_runtime.h>
#include <math.h>

typedef unsigned int u32;
typedef unsigned short u16;
typedef __attribute__((ext_vector_type(8))) short short8;
typedef __attribute__((ext_vector_type(4))) float f32x4;

__device__ __forceinline__ u16 f2bf(float f) {
  u32 u = __builtin_bit_cast(u32, f);
  u += 0x7FFFu + ((u >> 16) & 1u);
  return (u16)(u >> 16);
}
__device__ __forceinline__ float bf2f(u16 h) {
  u32 u = ((u32)h) << 16;
  return __builtin_bit_cast(float, u);
}
__device__ __forceinline__ void gload_lds16(const void* g, void* l) {
  __builtin_amdgcn_global_load_lds((const __attribute__((address_space(1))) u32*)g,
                                   (__attribute__((address_space(3))) u32*)l, 16, 0, 0);
}
__device__ __forceinline__ f32x4 mfma16(short8 a, short8 b, f32x4 c) {
  return __builtin_amdgcn_mfma_f32_16x16x32_bf16(a, b, c, 0, 0, 0);
}

// ------- transpose+cast (4 square weights, z-indexed): fp32 [K][N] -> bf16 [N][K] -------
__global__ __launch_bounds__(256) void transpose_cast4(const float* __restrict__ Wq,
                                                       const float* __restrict__ Wk,
                                                       const float* __restrict__ Wv,
                                                       const float* __restrict__ Wp,
                                                       u16* __restrict__ wqkvT,
                                                       u16* __restrict__ wpT) {
  __shared__ __attribute__((aligned(16))) u16 tile[64][72];
  const int z = blockIdx.z;
  const float* src = (z == 0) ? Wq : (z == 1) ? Wk : (z == 2) ? Wv : Wp;
  u16* dst = (z < 3) ? (wqkvT + (size_t)z * 2048 * 2048) : wpT;
  const int n0 = blockIdx.x * 64, k0 = blockIdx.y * 64;
  const int t = threadIdx.x;
  const int tr = t >> 4;
  const int tc4 = (t & 15) * 4;
#pragma unroll
  for (int p = 0; p < 4; ++p) {
    int row = p * 16 + tr;
    const float4 v = *(const float4*)(src + (size_t)(k0 + row) * 2048 + n0 + tc4);
    tile[tc4 + 0][row] = f2bf(v.x);
    tile[tc4 + 1][row] = f2bf(v.y);
    tile[tc4 + 2][row] = f2bf(v.z);
    tile[tc4 + 3][row] = f2bf(v.w);
  }
  __syncthreads();
  const int nr = t >> 2;
  const int kc = (t & 3) * 16;
  u16* d = dst + (size_t)(n0 + nr) * 2048 + k0 + kc;
  *(short8*)(d) = *(const short8*)&tile[nr][kc];
  *(short8*)(d + 8) = *(const short8*)&tile[nr][kc + 8];
}

// ------- transpose+cast W1 & W2 (z-indexed): fp32 [K][N] -> bf16 [N][K] ----------------
__global__ __launch_bounds__(256) void transpose_w12(const float* __restrict__ W1,
                                                     const float* __restrict__ W2,
                                                     u16* __restrict__ w1T,
                                                     u16* __restrict__ w2T) {
  __shared__ __attribute__((aligned(16))) u16 tile[64][72];
  const int z = blockIdx.z;
  const float* src = z ? W2 : W1;
  u16* dst = z ? w2T : w1T;
  const int K = z ? 8192 : 2048;
  const int N = z ? 2048 : 8192;
  const int n0 = (z ? blockIdx.y : blockIdx.x) * 64;
  const int k0 = (z ? blockIdx.x : blockIdx.y) * 64;
  const int t = threadIdx.x;
  const int tr = t >> 4;
  const int tc4 = (t & 15) * 4;
#pragma unroll
  for (int p = 0; p < 4; ++p) {
    int row = p * 16 + tr;
    const float4 v = *(const float4*)(src + (size_t)(k0 + row) * N + n0 + tc4);
    tile[tc4 + 0][row] = f2bf(v.x);
    tile[tc4 + 1][row] = f2bf(v.y);
    tile[tc4 + 2][row] = f2bf(v.z);
    tile[tc4 + 3][row] = f2bf(v.w);
  }
  __syncthreads();
  const int nr = t >> 2;
  const int kc = (t & 3) * 16;
  u16* d = dst + (size_t)(n0 + nr) * K + k0 + kc;
  *(short8*)(d) = *(const short8*)&tile[nr][kc];
  *(short8*)(d + 8) = *(const short8*)&tile[nr][kc + 8];
}

// ---------------- transpose V out of qkv: -> vT[h][d][kv] ----------------
__global__ __launch_bounds__(256) void transpose_v(const u16* __restrict__ qkv,
                                                   u16* __restrict__ vT) {
  __shared__ __attribute__((aligned(16))) u16 tile[64][72];
  const int kv0 = blockIdx.x * 64, d0 = blockIdx.y * 64, h = blockIdx.z;
  const int t = threadIdx.x;
  const int tr = t >> 3;
  const int tc8 = (t & 7) * 8;
#pragma unroll
  for (int p = 0; p < 2; ++p) {
    int row = p * 32 + tr;
    short8 v = *(const short8*)(qkv + (size_t)(kv0 + row) * 6144 + 4096 + h * 128 + d0 + tc8);
#pragma unroll
    for (int j = 0; j < 8; ++j) tile[tc8 + j][row] = (u16)v[j];
  }
  __syncthreads();
  const int dr = t >> 2;
  const int kc = (t & 3) * 16;
  u16* dst = vT + ((size_t)h * 128 + d0 + dr) * 2048 + kv0 + kc;
  *(short8*)dst = *(const short8*)&tile[dr][kc];
  *(short8*)(dst + 8) = *(const short8*)&tile[dr][kc + 8];
}

// ---------------- LayerNorm: fp32 [2048 rows][2048] -> bf16 ----------------
__global__ __launch_bounds__(256) void ln_kernel(const float* __restrict__ x,
                                                 const float* __restrict__ gw,
                                                 const float* __restrict__ bw,
                                                 u16* __restrict__ out) {
  const int row = blockIdx.x, t = threadIdx.x;
  const float* xr = x + (size_t)row * 2048;
  const float4 v0 = *(const float4*)(xr + t * 8);
  const float4 v1 = *(const float4*)(xr + t * 8 + 4);
  float s = v0.x + v0.y + v0.z + v0.w + v1.x + v1.y + v1.z + v1.w;
  float q = v0.x * v0.x + v0.y * v0.y + v0.z * v0.z + v0.w * v0.w +
            v1.x * v1.x + v1.y * v1.y + v1.z * v1.z + v1.w * v1.w;
#pragma unroll
  for (int w = 32; w; w >>= 1) { s += __shfl_xor(s, w); q += __shfl_xor(q, w); }
  __shared__ float rs[4], rq[4];
  const int wid = t >> 6, lane = t & 63;
  if (!lane) { rs[wid] = s; rq[wid] = q; }
  __syncthreads();
  s = rs[0] + rs[1] + rs[2] + rs[3];
  q = rq[0] + rq[1] + rq[2] + rq[3];
  const float mu = s * (1.f / 2048.f);
  const float var = q * (1.f / 2048.f) - mu * mu;
  const float rstd = rsqrtf(var + 1e-5f);
  const float4 g0 = *(const float4*)(gw + t * 8);
  const float4 g1 = *(const float4*)(gw + t * 8 + 4);
  const float4 b0 = *(const float4*)(bw + t * 8);
  const float4 b1 = *(const float4*)(bw + t * 8 + 4);
  short8 o;
  o[0] = (short)f2bf((v0.x - mu) * rstd * g0.x + b0.x);
  o[1] = (short)f2bf((v0.y - mu) * rstd * g0.y + b0.y);
  o[2] = (short)f2bf((v0.z - mu) * rstd * g0.z + b0.z);
  o[3] = (short)f2bf((v0.w - mu) * rstd * g0.w + b0.w);
  o[4] = (short)f2bf((v1.x - mu) * rstd * g1.x + b1.x);
  o[5] = (short)f2bf((v1.y - mu) * rstd * g1.y + b1.y);
  o[6] = (short)f2bf((v1.z - mu) * rstd * g1.z + b1.z);
  o[7] = (short)f2bf((v1.w - mu) * rstd * g1.w + b1.w);
  *(short8*)(out + (size_t)row * 2048 + t * 8) = o;
}

// ------- fused split-K reduce + LayerNorm: x1 = sum(partials)+bias+x; g = LN(x1) -------
__global__ __launch_bounds__(256) void reduce_ln(const float* __restrict__ pA,
                                                 const float* __restrict__ pB,
                                                 const float* __restrict__ bias,
                                                 const float* __restrict__ res1,
                                                 const float* __restrict__ gw,
                                                 const float* __restrict__ bw,
                                                 float* __restrict__ x1,
                                                 u16* __restrict__ g) {
  const int row = blockIdx.x, t = threadIdx.x;
  const size_t MN = 4194304;
  const size_t base = (size_t)row * 2048 + t * 8;
  float v[8];
#pragma unroll
  for (int half = 0; half < 2; ++half) {
    float4 a0 = *(const float4*)(pA + base + half * 4);
    float4 a1 = *(const float4*)(pA + MN + base + half * 4);
    float4 b0 = *(const float4*)(pB + base + half * 4);
    float4 b1 = *(const float4*)(pB + MN + base + half * 4);
    float4 bi = *(const float4*)(bias + t * 8 + half * 4);
    float4 r1 = *(const float4*)(res1 + base + half * 4);
    v[half * 4 + 0] = a0.x + a1.x + b0.x + b1.x + bi.x + r1.x;
    v[half * 4 + 1] = a0.y + a1.y + b0.y + b1.y + bi.y + r1.y;
    v[half * 4 + 2] = a0.z + a1.z + b0.z + b1.z + bi.z + r1.z;
    v[half * 4 + 3] = a0.w + a1.w + b0.w + b1.w + bi.w + r1.w;
  }
  float4 o0 = {v[0], v[1], v[2], v[3]}, o1 = {v[4], v[5], v[6], v[7]};
  *(float4*)(x1 + base) = o0;
  *(float4*)(x1 + base + 4) = o1;
  float s = 0.f, q = 0.f;
#pragma unroll
  for (int j = 0; j < 8; ++j) { s += v[j]; q += v[j] * v[j]; }
#pragma unroll
  for (int w = 32; w; w >>= 1) { s += __shfl_xor(s, w); q += __shfl_xor(q, w); }
  __shared__ float rs[4], rq[4];
  const int wid = t >> 6, lane = t & 63;
  if (!lane) { rs[wid] = s; rq[wid] = q; }
  __syncthreads();
  s = rs[0] + rs[1] + rs[2] + rs[3];
  q = rq[0] + rq[1] + rq[2] + rq[3];
  const float mu = s * (1.f / 2048.f);
  const float var = q * (1.f / 2048.f) - mu * mu;
  const float rstd = rsqrtf(var + 1e-5f);
  short8 o;
#pragma unroll
  for (int j = 0; j < 8; ++j) {
    float gj = *(gw + t * 8 + j);
    float bj = *(bw + t * 8 + j);
    o[j] = (short)f2bf((v[j] - mu) * rstd * gj + bj);
  }
  *(short8*)(g + base) = o;
}

// ---------------- GEMM v3 (best): 256x256, BK=32, 8 waves (2Mx4N), triple-buffer -------
// EPI 2 epilogue uses tanh-GELU (x * sigmoid(2u)) via __expf.
template <int EPI>
__global__ __launch_bounds__(512, 2) void gemm3(const u16* __restrict__ A,
                                                const u16* __restrict__ Bt,
                                                int M, int N, int K, int Kc,
                                                u16* __restrict__ outB,
                                                const float* __restrict__ bias,
                                                float* __restrict__ pA,
                                                float* __restrict__ pB) {
  __shared__ __attribute__((aligned(16))) u16 lds[3 * 16384];
  const int m0 = blockIdx.y * 256, n0 = blockIdx.x * 256;
  const int tid = threadIdx.x, wid = tid >> 6, lane = tid & 63;
  const int wr = wid >> 2, wc = wid & 3;
  const int lq = lane & 15, lk = lane >> 4;
  const int kStart = blockIdx.z * Kc;
  const int NT = Kc / 32;

  size_t aoff[2], boff[2];
#pragma unroll
  for (int s = 0; s < 2; ++s) {
    int c = s * 512 + tid;
    int row = c >> 2;
    int col = ((c & 3) ^ ((row >> 1) & 3)) * 8;
    aoff[s] = (size_t)(m0 + row) * K + kStart + col;
    boff[s] = (size_t)(n0 + row) * K + kStart + col;
  }
  u16* ldst = lds + tid * 8;

#define STA(s, buf, t2) gload_lds16(A + aoff[s] + (size_t)((t2) * 32), \
                                    ldst + (buf) * 16384 + (s) * 4096)
#define STB(s, buf, t2) gload_lds16(Bt + boff[s] + (size_t)((t2) * 32), \
                                    ldst + (buf) * 16384 + 8192 + (s) * 4096)

  STA(0, 0, 0); STA(1, 0, 0); STB(0, 0, 0); STB(1, 0, 0);
  STA(0, 1, 1); STA(1, 1, 1); STB(0, 1, 1); STB(1, 1, 1);
  asm volatile("s_waitcnt vmcnt(4)" ::: "memory");
  __builtin_amdgcn_s_barrier();
  __builtin_amdgcn_sched_barrier(0);

  f32x4 acc[8][4] = {};
  int cur = 0, nxt2 = 2;
  for (int t = 0; t < NT; ++t) {
    const char* bufc = (const char*)lds + cur * 32768;
    const bool st = (t + 2) < NT;
    short8 bf[4], af[4];
#pragma unroll
    for (int ni = 0; ni < 4; ++ni) {
      int br = wc * 64 + ni * 16 + lq;
      bf[ni] = *(const short8*)(bufc + 16384 + br * 64 + ((lk ^ ((br >> 1) & 3)) << 4));
    }
#pragma unroll
    for (int mi = 0; mi < 4; ++mi) {
      int ar = wr * 128 + mi * 16 + lq;
      af[mi] = *(const short8*)(bufc + ar * 64 + ((lk ^ ((ar >> 1) & 3)) << 4));
    }
    if (st) { STA(0, nxt2, t + 2); STA(1, nxt2, t + 2); }
    __builtin_amdgcn_s_setprio(1);
#pragma unroll
    for (int mi = 0; mi < 4; ++mi)
#pragma unroll
      for (int ni = 0; ni < 4; ++ni)
        acc[mi][ni] = mfma16(af[mi], bf[ni], acc[mi][ni]);
    __builtin_amdgcn_s_setprio(0);
#pragma unroll
    for (int mi = 0; mi < 4; ++mi) {
      int ar = wr * 128 + (mi + 4) * 16 + lq;
      af[mi] = *(const short8*)(bufc + ar * 64 + ((lk ^ ((ar >> 1) & 3)) << 4));
    }
    if (st) { STB(0, nxt2, t + 2); STB(1, nxt2, t + 2); }
    __builtin_amdgcn_s_setprio(1);
#pragma unroll
    for (int mi = 0; mi < 4; ++mi)
#pragma unroll
      for (int ni = 0; ni < 4; ++ni)
        acc[mi + 4][ni] = mfma16(af[mi], bf[ni], acc[mi + 4][ni]);
    __builtin_amdgcn_s_setprio(0);
    if (st) asm volatile("s_waitcnt vmcnt(4)" ::: "memory");
    else    asm volatile("s_waitcnt vmcnt(0)" ::: "memory");
    __builtin_amdgcn_s_barrier();
    __builtin_amdgcn_sched_barrier(0);
    cur = (cur == 2) ? 0 : cur + 1;
    nxt2 = (nxt2 == 2) ? 0 : nxt2 + 1;
  }
#undef STA
#undef STB

  float* pp = nullptr;
  if (EPI == 4) {
    pp = (blockIdx.z < 2 ? pA : pB) + (size_t)(blockIdx.z & 1) * ((size_t)M * N);
  }
#pragma unroll
  for (int mi = 0; mi < 8; ++mi) {
#pragma unroll
    for (int ni = 0; ni < 4; ++ni) {
      const int col = n0 + wc * 64 + ni * 16 + lq;
#pragma unroll
      for (int r = 0; r < 4; ++r) {
        const int row = m0 + wr * 128 + mi * 16 + lk * 4 + r;
        const size_t idx = (size_t)row * N + col;
        float v = acc[mi][ni][r];
        if (EPI == 0) {
          outB[idx] = f2bf(v);
        } else if (EPI == 2) {
          float xg = v + bias[col];
          float u = 0.7978845608f * (xg + 0.044715f * xg * xg * xg);
          outB[idx] = f2bf(xg / (1.f + __expf(-2.f * u)));
        } else {
          pp[idx] = v;
        }
      }
    }
  }
}

// ---------------- GEMM v5 (QKV): 256x128 tile, BK=32, 8 waves (4Mx2N), 72KB ------------
template <int EPI>
__global__ __launch_bounds__(512, 4) void gemm5(const u16* __restrict__ A,
                                                const u16* __restrict__ Bt,
                                                int M, int N, int K, int Kc,
                                                u16* __restrict__ outB,
                                                const float* __restrict__ bias,
                                                float* __restrict__ pA,
                                                float* __restrict__ pB) {
  __shared__ __attribute__((aligned(16))) u16 lds[3 * 12288];
  const int m0 = blockIdx.y * 256, n0 = blockIdx.x * 128;
  const int tid = threadIdx.x, wid = tid >> 6, lane = tid & 63;
  const int wr = wid >> 1, wc = wid & 1;
  const int lq = lane & 15, lk = lane >> 4;
  const int kStart = blockIdx.z * Kc;
  const int NT = Kc / 32;

  size_t aoff[2], boff;
#pragma unroll
  for (int s = 0; s < 2; ++s) {
    int c = s * 512 + tid;
    int row = c >> 2;
    int col = ((c & 3) ^ ((row >> 1) & 3)) * 8;
    aoff[s] = (size_t)(m0 + row) * K + kStart + col;
  }
  {
    int row = tid >> 2;
    int col = ((tid & 3) ^ ((row >> 1) & 3)) * 8;
    boff = (size_t)(n0 + row) * K + kStart + col;
  }
  u16* ldst = lds + tid * 8;

#define STA(s, buf, t2) gload_lds16(A + aoff[s] + (size_t)((t2) * 32), \
                                    ldst + (buf) * 12288 + (s) * 4096)
#define STB(buf, t2) gload_lds16(Bt + boff + (size_t)((t2) * 32), \
                                 ldst + (buf) * 12288 + 8192)

  STA(0, 0, 0); STA(1, 0, 0); STB(0, 0);
  STA(0, 1, 1); STA(1, 1, 1); STB(1, 1);
  asm volatile("s_waitcnt vmcnt(3)" ::: "memory");
  __builtin_amdgcn_s_barrier();
  __builtin_amdgcn_sched_barrier(0);

  f32x4 acc[4][4] = {};
  int cur = 0, nxt2 = 2;
  for (int t = 0; t < NT; ++t) {
    const char* bufc = (const char*)lds + cur * 24576;
    const bool st = (t + 2) < NT;
    short8 bf[4], af[4];
#pragma unroll
    for (int ni = 0; ni < 4; ++ni) {
      int br = wc * 64 + ni * 16 + lq;
      bf[ni] = *(const short8*)(bufc + 16384 + br * 64 + ((lk ^ ((br >> 1) & 3)) << 4));
    }
#pragma unroll
    for (int mi = 0; mi < 4; ++mi) {
      int ar = wr * 64 + mi * 16 + lq;
      af[mi] = *(const short8*)(bufc + ar * 64 + ((lk ^ ((ar >> 1) & 3)) << 4));
    }
    if (st) { STA(0, nxt2, t + 2); STA(1, nxt2, t + 2); STB(nxt2, t + 2); }
    __builtin_amdgcn_s_setprio(1);
#pragma unroll
    for (int mi = 0; mi < 4; ++mi)
#pragma unroll
      for (int ni = 0; ni < 4; ++ni)
        acc[mi][ni] = mfma16(af[mi], bf[ni], acc[mi][ni]);
    __builtin_amdgcn_s_setprio(0);
    if (st) asm volatile("s_waitcnt vmcnt(3)" ::: "memory");
    else    asm volatile("s_waitcnt vmcnt(0)" ::: "memory");
    __builtin_amdgcn_s_barrier();
    __builtin_amdgcn_sched_barrier(0);
    cur = (cur == 2) ? 0 : cur + 1;
    nxt2 = (nxt2 == 2) ? 0 : nxt2 + 1;
  }
#undef STA
#undef STB

  float* pp = nullptr;
  if (EPI == 4) {
    pp = (blockIdx.z < 2 ? pA : pB) + (size_t)(blockIdx.z & 1) * ((size_t)M * N);
  }
#pragma unroll
  for (int mi = 0; mi < 4; ++mi) {
#pragma unroll
    for (int ni = 0; ni < 4; ++ni) {
      const int col = n0 + wc * 64 + ni * 16 + lq;
#pragma unroll
      for (int r = 0; r < 4; ++r) {
        const int row = m0 + wr * 64 + mi * 16 + lk * 4 + r;
        const size_t idx = (size_t)row * N + col;
        float v = acc[mi][ni][r];
        if (EPI == 0) {
          outB[idx] = f2bf(v);
        } else if (EPI == 2) {
          float xg = v + bias[col];
          float u = 0.7978845608f * (xg + 0.044715f * xg * xg * xg);
          outB[idx] = f2bf(xg / (1.f + __expf(-2.f * u)));
        } else {
          pp[idx] = v;
        }
      }
    }
  }
}

// ---------------- split-K reduce: out = sum partials + bias + res1 (+ bf(res2)) --------
template <int NS, int RES2>
__global__ __launch_bounds__(256) void reduce_kernel(const float* __restrict__ pA,
                                                     const float* __restrict__ pB,
                                                     const float* __restrict__ bias,
                                                     const float* __restrict__ res1,
                                                     const u16* __restrict__ res2,
                                                     float* __restrict__ out,
                                                     int MN, int N) {
  const int i = (blockIdx.x * 256 + threadIdx.x) * 4;
  if (i >= MN) return;
  float4 s = *(const float4*)(pA + i);
  {
    const float4 t = *(const float4*)(pA + MN + i);
    s.x += t.x; s.y += t.y; s.z += t.z; s.w += t.w;
  }
  if (NS == 4) {
    const float4 t0 = *(const float4*)(pB + i);
    const float4 t1 = *(const float4*)(pB + MN + i);
    s.x += t0.x + t1.x; s.y += t0.y + t1.y; s.z += t0.z + t1.z; s.w += t0.w + t1.w;
  }
  const int col = i & (N - 1);
  const float4 bv = *(const float4*)(bias + col);
  const float4 r1 = *(const float4*)(res1 + i);
  float4 o;
  o.x = s.x + bv.x + r1.x;
  o.y = s.y + bv.y + r1.y;
  o.z = s.z + bv.z + r1.z;
  o.w = s.w + bv.w + r1.w;
  if (RES2) {
    const u16* r2 = res2 + i;
    o.x += bf2f(r2[0]); o.y += bf2f(r2[1]); o.z += bf2f(r2[2]); o.w += bf2f(r2[3]);
  }
  *(float4*)(out + i) = o;
}

// ------- flash attention (causal), split-KV x2, 4 waves x 16 q-rows, KVBLK=64 ----------
// LDS-staged K/V (coalesced global_load_lds); single-buffer 40KB -> 4 blocks/CU.
__global__ __launch_bounds__(256) void attn_kernel(const u16* __restrict__ qkv,
                                                   const u16* __restrict__ vT,
                                                   float* __restrict__ po,
                                                   float* __restrict__ pm,
                                                   float* __restrict__ pl) {
  __shared__ __attribute__((aligned(16))) u16 lsK[64 * 128];
  __shared__ __attribute__((aligned(16))) u16 lsV[128 * 64];
  __shared__ __attribute__((aligned(16))) u16 lsP[4][16 * 64];
  const int h = blockIdx.x;
  const int c = blockIdx.y;
  const int qi = 31 - blockIdx.z;
  const int qb = qi * 64;
  const int tid = threadIdx.x, wid = tid >> 6, lane = tid & 63;
  const int lq = lane & 15, lk = lane >> 4;
  const int qw = qb + wid * 16;

  const int nkt = qi + 1;
  const int ch0 = (nkt + 1) >> 1;
  const int base = c ? ch0 : 0;
  const int cnt = c ? (nkt - ch0) : ch0;

  short8 qf[4];
  {
    const u16* qp = qkv + (size_t)(qw + lq) * 6144 + h * 128;
#pragma unroll
    for (int ks = 0; ks < 4; ++ks) qf[ks] = *(const short8*)(qp + ks * 32 + lk * 8);
  }
  float mreg[4], lreg[4];
  f32x4 o[8];
#pragma unroll
  for (int r = 0; r < 4; ++r) { mreg[r] = -INFINITY; lreg[r] = 0.f; }
#pragma unroll
  for (int dt = 0; dt < 8; ++dt) o[dt] = (f32x4){0.f, 0.f, 0.f, 0.f};

  const int rK = lane >> 4, sK = lane & 15;
  const int rV = lane >> 3, sV = lane & 7;
  for (int it = 0; it < cnt; ++it) {
    const int kt = base + it;
    const int kv0 = kt * 64;
    if (it) __syncthreads();
#pragma unroll
    for (int i = 0; i < 4; ++i) {
      int cc = wid * 4 + i;
      int rowK = cc * 4 + rK;
      gload_lds16(qkv + (size_t)(kv0 + rowK) * 6144 + 2048 + h * 128 + ((sK ^ (rowK & 7)) * 8),
                  lsK + cc * 512);
      int rowV = cc * 8 + rV;
      gload_lds16(vT + ((size_t)h * 128 + rowV) * 2048 + kv0 + ((sV ^ (rowV & 7)) * 8),
                  lsV + cc * 512);
    }
    __syncthreads();

    f32x4 sc[4];
#pragma unroll
    for (int nt = 0; nt < 4; ++nt) sc[nt] = (f32x4){0.f, 0.f, 0.f, 0.f};
#pragma unroll
    for (int ks = 0; ks < 4; ++ks) {
#pragma unroll
      for (int nt = 0; nt < 4; ++nt) {
        int kvr = nt * 16 + lq;
        short8 kf = *(const short8*)((const char*)lsK + kvr * 256 +
                                     ((ks * 64 + lk * 16) ^ ((kvr & 7) << 4)));
        sc[nt] = mfma16(qf[ks], kf, sc[nt]);
      }
    }
    float rmax[4] = {-INFINITY, -INFINITY, -INFINITY, -INFINITY};
#pragma unroll
    for (int nt = 0; nt < 4; ++nt) {
      int kv = kv0 + nt * 16 + lq;
#pragma unroll
      for (int r = 0; r < 4; ++r) {
        int qrow = qw + lk * 4 + r;
        float s = (kv <= qrow) ? sc[nt][r] * 0.08838834764831845f : -INFINITY;
        sc[nt][r] = s;
        rmax[r] = fmaxf(rmax[r], s);
      }
    }
#pragma unroll
    for (int r = 0; r < 4; ++r)
#pragma unroll
      for (int w = 1; w < 16; w <<= 1) rmax[r] = fmaxf(rmax[r], __shfl_xor(rmax[r], w));
    bool grow = false;
#pragma unroll
    for (int r = 0; r < 4; ++r) grow |= (rmax[r] > mreg[r] + 8.f);
    if (__any(grow)) {
#pragma unroll
      for (int r = 0; r < 4; ++r) {
        float mn = fmaxf(mreg[r], rmax[r]);
        float alpha = __expf(mreg[r] - mn);
        mreg[r] = mn;
        lreg[r] *= alpha;
#pragma unroll
        for (int dt = 0; dt < 8; ++dt) o[dt][r] *= alpha;
      }
    }
    float rsum[4] = {0.f, 0.f, 0.f, 0.f};
    u16* P = &lsP[wid][0];
#pragma unroll
    for (int nt = 0; nt < 4; ++nt) {
#pragma unroll
      for (int r = 0; r < 4; ++r) {
        float p = __expf(sc[nt][r] - mreg[r]);
        rsum[r] += p;
        int prow = lk * 4 + r, pcol = nt * 16 + lq;
        *(u16*)((char*)P + prow * 128 + ((pcol * 2) ^ ((prow & 7) << 4))) = f2bf(p);
      }
    }
#pragma unroll
    for (int r = 0; r < 4; ++r) {
#pragma unroll
      for (int w = 1; w < 16; w <<= 1) rsum[r] += __shfl_xor(rsum[r], w);
      lreg[r] += rsum[r];
    }
#pragma unroll
    for (int kk = 0; kk < 2; ++kk) {
      short8 pa = *(const short8*)((const char*)P + lq * 128 +
                                   ((kk * 64 + lk * 16) ^ ((lq & 7) << 4)));
#pragma unroll
      for (int dt = 0; dt < 8; ++dt) {
        int dr = dt * 16 + lq;
        short8 vf = *(const short8*)((const char*)lsV + dr * 128 +
                                     ((kk * 64 + lk * 16) ^ ((dr & 7) << 4)));
        o[dt] = mfma16(pa, vf, o[dt]);
      }
    }
  }
#pragma unroll
  for (int r = 0; r < 4; ++r) {
    int row = qw + lk * 4 + r;
    float* op = po + (size_t)c * 4194304 + ((size_t)h * 2048 + row) * 128 + lq;
#pragma unroll
    for (int dt = 0; dt < 8; ++dt) op[dt * 16] = o[dt][r];
    if (lq == 0) {
      pm[c * 32768 + h * 2048 + row] = mreg[r];
      pl[c * 32768 + h * 2048 + row] = lreg[r];
    }
  }
}

// ---------------- merge split-KV partials -> attn bf16 [row][h*128+d] ----------------
__global__ __launch_bounds__(256) void attn_merge(const float* __restrict__ po,
                                                  const float* __restrict__ pm,
                                                  const float* __restrict__ pl,
                                                  u16* __restrict__ attn) {
  const int e = (blockIdx.x * 256 + threadIdx.x) * 4;
  const int hrow = e >> 7;
  const int d = e & 127;
  const int h = hrow >> 11, row = hrow & 2047;
  float m0 = pm[hrow], m1 = pm[32768 + hrow];
  float l0 = pl[hrow], l1 = pl[32768 + hrow];
  float m = fmaxf(m0, m1);
  float w0 = __expf(m0 - m), w1 = __expf(m1 - m);
  float inv = 1.f / (l0 * w0 + l1 * w1);
  float4 o0 = *(const float4*)(po + e);
  float4 o1 = *(const float4*)(po + 4194304 + e);
  u16* op = attn + (size_t)row * 2048 + h * 128 + d;
  op[0] = f2bf((o0.x * w0 + o1.x * w1) * inv);
  op[1] = f2bf((o0.y * w0 + o1.y * w1) * inv);
  op[2] = f2bf((o0.z * w0 + o1.z * w1) * inv);
  op[3] = f2bf((o0.w * w0 + o1.w * w1) * inv);
}

extern "C" void kernel_launch(void* const* d_in, const int* in_sizes, int n_in,
                              void* d_out, int out_size, void* d_ws, size_t ws_size,
                              hipStream_t stream) {
  (void)in_sizes; (void)n_in; (void)out_size; (void)ws_size;
  const float* x    = (const float*)d_in[0];
  const float* ln1g = (const float*)d_in[1];
  const float* ln1b = (const float*)d_in[2];
  const float* Wq   = (const float*)d_in[3];
  const float* Wk   = (const float*)d_in[4];
  const float* Wv   = (const float*)d_in[5];
  const float* Wp   = (const float*)d_in[6];
  const float* bp   = (const float*)d_in[7];
  const float* ln2g = (const float*)d_in[8];
  const float* ln2b = (const float*)d_in[9];
  const float* W1   = (const float*)d_in[10];
  const float* b1   = (const float*)d_in[11];
  const float* W2   = (const float*)d_in[12];
  const float* b2   = (const float*)d_in[13];
  float* out = (float*)d_out;
  char* ws = (char*)d_ws;

  u16* wqkvT = (u16*)(ws + 0);
  u16* hbuf  = (u16*)(ws + 25165824);
  u16* wpT   = (u16*)(ws + 33554432);
  u16* w1T   = (u16*)(ws + 41943040);
  u16* w2T   = (u16*)(ws + 75497472);
  u16* qkv   = (u16*)(ws + 109051904);
  u16* vT    = (u16*)(ws + 134217728);
  u16* attn  = (u16*)(ws + 142606336);
  float* x1  = (float*)(ws + 150994944);
  u16* g     = (u16*)(ws + 167772160);
  u16* ff1   = (u16*)(ws + 0);
  float* po = (float*)(ws + 0);
  float* pm = (float*)(ws + 167772160);
  float* pl = (float*)(ws + 167772160 + 262144);
  float* projPA = (float*)(ws + 0);
  float* projPB = (float*)(ws + 109051904);
  float* ffPA = (float*)(ws + 33554432);
  float* ffPB = (float*)(ws + 109051904);

  dim3 b256(256), b512(512);
  transpose_cast4<<<dim3(32, 32, 4), b256, 0, stream>>>(Wq, Wk, Wv, Wp, wqkvT, wpT);
  transpose_w12<<<dim3(128, 32, 2), b256, 0, stream>>>(W1, W2, w1T, w2T);
  ln_kernel<<<2048, b256, 0, stream>>>(x, ln1g, ln1b, hbuf);
  gemm5<0><<<dim3(48, 8, 1), b512, 0, stream>>>(hbuf, wqkvT, 2048, 6144, 2048, 2048,
                                                qkv, nullptr, nullptr, nullptr);
  transpose_v<<<dim3(32, 2, 16), b256, 0, stream>>>(qkv, vT);
  attn_kernel<<<dim3(16, 2, 32), b256, 0, stream>>>(qkv, vT, po, pm, pl);
  attn_merge<<<4096, b256, 0, stream>>>(po, pm, pl, attn);
  gemm3<4><<<dim3(8, 8, 4), b512, 0, stream>>>(attn, wpT, 2048, 2048, 2048, 512,
                                               nullptr, nullptr, projPA, projPB);
  reduce_ln<<<2048, b256, 0, stream>>>(projPA, projPB, bp, x, ln2g, ln2b, x1, g);
  gemm3<2><<<dim3(32, 8, 1), b512, 0, stream>>>(g, w1T, 2048, 8192, 2048, 2048,
                                                ff1, b1, nullptr, nullptr);
  gemm3<4><<<dim3(8, 8, 4), b512, 0, stream>>>(ff1, w2T, 2048, 2048, 8192, 2048,
                                               nullptr, nullptr, ffPA, ffPB);
  reduce_kernel<4, 1><<<4096, b256, 0, stream>>>(ffPA, ffPB, b2, x1, g, out,
                                                 4194304, 2048);
}